// Round 10
// baseline (261.571 us; speedup 1.0000x reference)
//
#include <hip/hip_runtime.h>
#include <stdint.h>
#include <stddef.h>

#define DIM 1024
#define EPS 1e-8f

typedef __attribute__((ext_vector_type(4)))  int   i32x4;
typedef __attribute__((ext_vector_type(8)))  int   i32x8;
typedef __attribute__((ext_vector_type(4)))  float f32x4;

// e8m0 scale byte 123 = 2^(123-127) = 1/16 per operand -> 1/256 on the product,
// exactly cancelling the x16 prep scaling (bit-exact pow2 exponent shift).
#define SCALE8 0x7B7B7B7B

// async global->LDS, 16B per lane, wave-uniform LDS base + lane*16
__device__ __forceinline__ void async_copy16(const void* g, void* l) {
    __builtin_amdgcn_global_load_lds(
        (__attribute__((address_space(1))) void*)const_cast<void*>(g),
        (__attribute__((address_space(3))) void*)(l), 16, 0, 0);
}

// ---------------------------------------------------------------------------
// Prep: wave-per-row. Unit-normalize, scale by 16 (undone by hw e8m0 scales in
// the GEMM), cast to OCP fp8 e4m3, store rows LINEARLY. This round: per-lane
// 64-B granularity -> ONE dwordx4 store per lane (was 4 dword stores).
// Lane L handles floats [16L, 16L+16) of its row; reduction unchanged.
// Also zeroes the gemm done-counter (fused-loss support).
// ---------------------------------------------------------------------------
__global__ __launch_bounds__(256)
void prep_all(const float* __restrict__ x, const float* __restrict__ pos,
              const float* __restrict__ neg,
              unsigned char* __restrict__ Xn, unsigned char* __restrict__ Nn,
              float* __restrict__ simOut, float* __restrict__ rowsum,
              unsigned int* __restrict__ counter, int bn) {
    const int lane = threadIdx.x & 63;
    const int wave = threadIdx.x >> 6;
    const int grow = blockIdx.x * 4 + wave;
    const bool isX = grow < bn;
    const int row  = isX ? grow : grow - bn;
    const float* src = isX ? x : neg;
    unsigned char* dst = isX ? Xn : Nn;

    if (grow == 0 && lane == 0) *counter = 0u;   // reset fused-loss counter

    const float4* s = (const float4*)(src + (size_t)row * DIM) + 4 * lane;
    float4 xv[4], pv[4];
    float sxx = 0.f, spp = 0.f, sxp = 0.f;
#pragma unroll
    for (int i = 0; i < 4; i++) {
        xv[i] = s[i];
        sxx += xv[i].x * xv[i].x + xv[i].y * xv[i].y + xv[i].z * xv[i].z + xv[i].w * xv[i].w;
    }
    if (isX) {
        const float4* p = (const float4*)(pos + (size_t)row * DIM) + 4 * lane;
#pragma unroll
        for (int i = 0; i < 4; i++) {
            pv[i] = p[i];
            spp += pv[i].x * pv[i].x + pv[i].y * pv[i].y + pv[i].z * pv[i].z + pv[i].w * pv[i].w;
            sxp += xv[i].x * pv[i].x + xv[i].y * pv[i].y + xv[i].z * pv[i].z + xv[i].w * pv[i].w;
        }
#pragma unroll
        for (int off = 1; off < 64; off <<= 1) {
            sxx += __shfl_xor(sxx, off);
            spp += __shfl_xor(spp, off);
            sxp += __shfl_xor(sxp, off);
        }
    } else {
#pragma unroll
        for (int off = 1; off < 64; off <<= 1) sxx += __shfl_xor(sxx, off);
    }
    const float nx  = sqrtf(sxx);
    const float inv = (nx > 0.f) ? (16.f / nx) : 0.f;   // x16 -> e4m3 sweet spot
    if (isX && lane == 0) {
        const float np = sqrtf(spp);
        simOut[row] = sxp / fmaxf(nx * np, EPS);
        rowsum[row] = 0.f;
    }
    unsigned int t;
    t = __builtin_amdgcn_cvt_pk_fp8_f32(xv[0].x * inv, xv[0].y * inv, 0, false);
    unsigned int q0 = __builtin_amdgcn_cvt_pk_fp8_f32(xv[0].z * inv, xv[0].w * inv, t, true);
    t = __builtin_amdgcn_cvt_pk_fp8_f32(xv[1].x * inv, xv[1].y * inv, 0, false);
    unsigned int q1 = __builtin_amdgcn_cvt_pk_fp8_f32(xv[1].z * inv, xv[1].w * inv, t, true);
    t = __builtin_amdgcn_cvt_pk_fp8_f32(xv[2].x * inv, xv[2].y * inv, 0, false);
    unsigned int q2 = __builtin_amdgcn_cvt_pk_fp8_f32(xv[2].z * inv, xv[2].w * inv, t, true);
    t = __builtin_amdgcn_cvt_pk_fp8_f32(xv[3].x * inv, xv[3].y * inv, 0, false);
    unsigned int q3 = __builtin_amdgcn_cvt_pk_fp8_f32(xv[3].z * inv, xv[3].w * inv, t, true);

    // lane L holds row bytes [16L, 16L+16) -> one coalesced 16-B store.
    uint4 qv; qv.x = q0; qv.y = q1; qv.z = q2; qv.w = q3;
    *((uint4*)(dst + (size_t)row * DIM) + lane) = qv;
}

// ---------------------------------------------------------------------------
// Fused MX-fp8 GEMM + loss: rowsum[i] += sum_j exp(unit(x_i).unit(neg_j));
// the LAST block (device-scope done-counter) computes the scalar loss.
// K-loop is R4 VERBATIM (measured best: 66 us, no spill): 256x128 tile,
// 8 waves, per-wave 64x64 (4x4 frags of mfma_scale_f32_16x16x128_f8f6f4),
// BK=128-B windows, 3-buffer rotation (144 KB dyn LDS), prefetch distance 2,
// counted s_waitcnt vmcnt(6) at window boundaries, 2 sub-phases per window.
// R5-R9 lesson: five alternative structures (32x32x64 cell, 2-buf drain,
// A-direct, 4-phase split) all lost to this one — frozen.
// Fused loss: after epilogue, threadfence + counter atomic; last block
// re-reads rowsum coherently via atomicAdd(p, 0.f) (device-scope, G16-safe:
// no ordering/residency assumptions, no waiting loops) and writes out[0].
// ---------------------------------------------------------------------------
__global__ __launch_bounds__(512, 2)
void gemm_exp_rowsum(const unsigned char* __restrict__ Xn,
                     const unsigned char* __restrict__ Nn,
                     float* __restrict__ rowsum,
                     const float* __restrict__ sim,
                     float* __restrict__ out,
                     unsigned int* __restrict__ counter, int bn) {
    constexpr int KB   = DIM;            // 1024 bytes per fp8 row
    constexpr int BK   = 128;            // bytes per k-window (K=128 elems)
    constexpr int BOFF = 256 * BK;       // B area offset within a buffer
    constexpr int BUFB = BOFF + 128 * BK;   // 48 KB: A(32K) then B(16K)
    extern __shared__ unsigned char smem[];     // 3 * BUFB = 144 KB

    const int tid  = threadIdx.x;
    const int lane = tid & 63;
    const int wave = tid >> 6;                 // 0..7

    // T1: bijective chunked XCD swizzle (nwg = 1024, divisible by 8) — R4.
    const int nwg  = gridDim.x * gridDim.y;
    const int bid  = blockIdx.y * gridDim.x + blockIdx.x;
    const int swz  = (bid & 7) * (nwg >> 3) + (bid >> 3);
    const int rowBase = (swz / gridDim.x) * 256;
    const int colBase = (swz % gridDim.x) * 128;

    const int srow = lane >> 3;
    const int sch  = (lane & 7) ^ srow;
    const unsigned char* gA = Xn + (size_t)(rowBase + wave * 32 + srow) * KB + sch * 16;
    const unsigned char* gB = Nn + (size_t)(colBase + wave * 16 + srow) * KB + sch * 16;

    const f32x4 fz = {0.f, 0.f, 0.f, 0.f};
    f32x4 acc[4][4];
#pragma unroll
    for (int mi = 0; mi < 4; mi++)
#pragma unroll
        for (int ni = 0; ni < 4; ni++) acc[mi][ni] = fz;

    const int m0   = (wave >> 1) * 64;   // 0,64,128,192
    const int n0   = (wave & 1) * 64;    // 0,64
    const int mrow = lane & 15;
    const int q    = lane >> 4;          // k-quarter: bytes [32q, 32q+32)
    const int c0   = ((2 * q) ^ (mrow & 7)) << 4;

    int aoff[4], boff[4];
#pragma unroll
    for (int i = 0; i < 4; i++) {
        aoff[i] = (m0 + 16 * i + mrow) * BK + c0;
        boff[i] = BOFF + (n0 + 16 * i + mrow) * BK + c0;
    }

#define STAGE_HALF(buf, stg, h)                                                \
    do {                                                                       \
        const int kq = (stg) * BK;                                             \
        unsigned char* Lb = smem + (buf) * BUFB;                               \
        async_copy16(gA + (size_t)(16 * (h)) * KB + kq,                        \
                     Lb + (wave * 32 + 16 * (h)) * BK);                        \
        async_copy16(gA + (size_t)(16 * (h) + 8) * KB + kq,                    \
                     Lb + (wave * 32 + 16 * (h) + 8) * BK);                    \
        async_copy16(gB + (size_t)(8 * (h)) * KB + kq,                         \
                     Lb + BOFF + (wave * 16 + 8 * (h)) * BK);                  \
    } while (0)

#define RD(base, off, dst)                                                     \
    do {                                                                       \
        i32x4 lo_ = *(const i32x4*)((base) + (off));                           \
        i32x4 hi_ = *(const i32x4*)((base) + ((off) ^ 16));                    \
        dst = __builtin_shufflevector(lo_, hi_, 0, 1, 2, 3, 4, 5, 6, 7);       \
    } while (0)

    // prologue: windows 0,1 in flight (12 ops); retire window 0, keep 6.
    STAGE_HALF(0, 0, 0);
    STAGE_HALF(0, 0, 1);
    STAGE_HALF(1, 1, 0);
    STAGE_HALF(1, 1, 1);
    asm volatile("s_waitcnt vmcnt(6)\n\ts_barrier" ::: "memory");

#pragma unroll
    for (int w = 0; w < 8; w++) {
        const int b  = w % 3;
        const int nb = (w + 2) % 3;
        const unsigned char* Ab = smem + b * BUFB;
        i32x8 Af[4], Bf[2];
        // ---- sub-phase 0: stage half 0 of w+2 | read A frags + B lo | 8 MFMA
        if (w < 6) STAGE_HALF(nb, w + 2, 0);
#pragma unroll
        for (int i = 0; i < 4; i++) RD(Ab, aoff[i], Af[i]);
#pragma unroll
        for (int i = 0; i < 2; i++) RD(Ab, boff[i], Bf[i]);
        __builtin_amdgcn_s_setprio(1);
#pragma unroll
        for (int mi = 0; mi < 4; mi++)
#pragma unroll
            for (int ni = 0; ni < 2; ni++)
                acc[mi][ni] = __builtin_amdgcn_mfma_scale_f32_16x16x128_f8f6f4(
                    Af[mi], Bf[ni], acc[mi][ni], 0, 0, 0, SCALE8, 0, SCALE8);
        __builtin_amdgcn_s_setprio(0);
        asm volatile("s_barrier" ::: "memory");
        // ---- sub-phase 1: stage half 1 of w+2 | read B hi | 8 MFMA
        if (w < 6) STAGE_HALF(nb, w + 2, 1);
#pragma unroll
        for (int i = 0; i < 2; i++) RD(Ab, boff[2 + i], Bf[i]);
        __builtin_amdgcn_s_setprio(1);
#pragma unroll
        for (int mi = 0; mi < 4; mi++)
#pragma unroll
            for (int ni = 0; ni < 2; ni++)
                acc[mi][2 + ni] = __builtin_amdgcn_mfma_scale_f32_16x16x128_f8f6f4(
                    Af[mi], Bf[ni], acc[mi][2 + ni], 0, 0, 0, SCALE8, 0, SCALE8);
        __builtin_amdgcn_s_setprio(0);
        // ---- window boundary: counted wait (never 0 until the tail)
        if (w < 6) {
            asm volatile("s_waitcnt vmcnt(6)\n\ts_barrier" ::: "memory");
        } else if (w == 6) {
            asm volatile("s_waitcnt vmcnt(0)\n\ts_barrier" ::: "memory");
        }
    }
#undef STAGE_HALF
#undef RD

    // epilogue (verified): 16x16 C/D layout col=lane&15, row=q*4+reg.
#pragma unroll
    for (int mi = 0; mi < 4; mi++) {
        float rs0 = 0.f, rs1 = 0.f, rs2 = 0.f, rs3 = 0.f;
#pragma unroll
        for (int ni = 0; ni < 4; ni++) {
            rs0 += __expf(acc[mi][ni].x);
            rs1 += __expf(acc[mi][ni].y);
            rs2 += __expf(acc[mi][ni].z);
            rs3 += __expf(acc[mi][ni].w);
        }
#pragma unroll
        for (int off = 1; off < 16; off <<= 1) {
            rs0 += __shfl_xor(rs0, off);
            rs1 += __shfl_xor(rs1, off);
            rs2 += __shfl_xor(rs2, off);
            rs3 += __shfl_xor(rs3, off);
        }
        if ((lane & 15) == 0) {
            const int r = rowBase + m0 + mi * 16 + q * 4;
            atomicAdd(&rowsum[r + 0], rs0);
            atomicAdd(&rowsum[r + 1], rs1);
            atomicAdd(&rowsum[r + 2], rs2);
            atomicAdd(&rowsum[r + 3], rs3);
        }
    }

    // ---- fused loss: last block to finish computes out[0].
    __threadfence();                 // release our rowsum atomics
    __syncthreads();                 // all LDS reads done before smem reuse
    volatile unsigned int* flag = (volatile unsigned int*)smem;
    if (tid == 0) {
        unsigned int old = atomicAdd(counter, 1u);
        flag[0] = (old == (unsigned int)(nwg - 1)) ? 1u : 0u;
    }
    __syncthreads();
    if (flag[0]) {
        __threadfence();             // acquire side
        float a = 0.f;
        for (int i = tid; i < bn; i += 512) {
            const float rs = atomicAdd(&rowsum[i], 0.0f);   // coherent read
            a += logf(rs) - sim[i];
        }
#pragma unroll
        for (int off = 1; off < 64; off <<= 1) a += __shfl_xor(a, off);
        volatile float* red = (volatile float*)(smem + 64);
        if (lane == 0) red[wave] = a;
        __syncthreads();
        if (tid == 0) {
            float t = 0.f;
#pragma unroll
            for (int i = 0; i < 8; i++) t += red[i];
            out[0] = t / (float)bn;
        }
    }
}

extern "C" void kernel_launch(void* const* d_in, const int* in_sizes, int n_in,
                              void* d_out, int out_size, void* d_ws, size_t ws_size,
                              hipStream_t stream) {
    const float* x   = (const float*)d_in[0];
    const float* pos = (const float*)d_in[1];
    const float* neg = (const float*)d_in[2];
    const int bn = in_sizes[0] / DIM;  // 4096
    const int cn = in_sizes[2] / DIM;  // 8192

    // ws layout: Xn fp8 [bn*DIM] | Nn fp8 [cn*DIM] | sim f32 [bn] |
    //            rowsum f32 [bn] | counter u32
    unsigned char* Xn = (unsigned char*)d_ws;
    unsigned char* Nn = Xn + (size_t)bn * DIM;
    float* sim    = (float*)(Nn + (size_t)cn * DIM);
    float* rowsum = sim + bn;
    unsigned int* counter = (unsigned int*)(rowsum + bn);

    // opt in to 144 KB dynamic LDS. Host-side attribute set — graph-safe.
    static bool attr_done = false;
    if (!attr_done) {
        (void)hipFuncSetAttribute((const void*)gemm_exp_rowsum,
                                  hipFuncAttributeMaxDynamicSharedMemorySize,
                                  147456);
        attr_done = true;
    }

    prep_all<<<dim3((bn + cn) / 4), dim3(256), 0, stream>>>(
        x, pos, neg, Xn, Nn, sim, rowsum, counter, bn);
    gemm_exp_rowsum<<<dim3(cn / 128, bn / 256), dim3(512), 147456, stream>>>(
        Xn, Nn, rowsum, sim, (float*)d_out, counter, bn);
}